// Round 13
// baseline (568.050 us; speedup 1.0000x reference)
//
#include <hip/hip_runtime.h>
#include <math.h>

#define NB 256
#define NT 128
#define NDW 300
#define NH 128
#define NTYPE 8
#define NLEVEL 13
#define NN (NB*NT)

#define NBK 104       // (height 0..12) x (type 0..7) node buckets
#define CBLOCKS 64
#define PBLOCKS 1024  // phase grid: 128 subs per type x 8 types

// ib layout (ints), at byte offset 32MB of d_ws
#define BC 0                    // [64][104] per-block counts
#define BB 6656                 // [64][104] per-block base offsets
#define OFF 13312               // [105] bucket starts
#define NODE_LIST 13440         // [NN]
#define CDESC 46208             // [NN] (clist_start<<8)|child_count
#define CLIST 78976             // [NN] children sorted by parent (deterministic)

typedef __attribute__((ext_vector_type(8))) short short8;
typedef __attribute__((ext_vector_type(4))) float f32x4;
union U16 { uint4 u; short8 s; };

__global__ __launch_bounds__(256) void count_kernel(const int* __restrict__ dep_type,
    const int* __restrict__ height, int* ib) {
  __shared__ int cnt[NBK];
  for (int u = threadIdx.x; u < NBK; u += 256) cnt[u] = 0;
  __syncthreads();
  for (int i = blockIdx.x*256 + threadIdx.x; i < NN; i += CBLOCKS*256)
    atomicAdd(&cnt[height[i]*NTYPE + dep_type[i]], 1);
  __syncthreads();
  for (int u = threadIdx.x; u < NBK; u += 256)
    ib[BC + blockIdx.x*NBK + u] = cnt[u];
}

__global__ __launch_bounds__(128) void scan_kernel(int* ib) {
  __shared__ int total[NBK], start[NBK];
  int u = threadIdx.x;
  if (u < NBK) {
    int acc = 0;
    for (int b = 0; b < CBLOCKS; b++) {
      ib[BB + b*NBK + u] = acc;
      acc += ib[BC + b*NBK + u];
    }
    total[u] = acc;
  }
  __syncthreads();
  if (u == 0) {
    int acc = 0;
    for (int e = 0; e < NBK; e++) { start[e] = acc; ib[OFF+e] = acc; acc += total[e]; }
    ib[OFF+NBK] = acc;
  }
  __syncthreads();
  if (u < NBK) {
    int s = start[u];
    for (int b = 0; b < CBLOCKS; b++) ib[BB + b*NBK + u] += s;
  }
}

__global__ __launch_bounds__(256) void scatter_kernel(const int* __restrict__ dep_type,
    const int* __restrict__ height, int* ib) {
  __shared__ int base[NBK];
  __shared__ int cnt[NBK];
  for (int u = threadIdx.x; u < NBK; u += 256) {
    base[u] = ib[BB + blockIdx.x*NBK + u];
    cnt[u] = 0;
  }
  __syncthreads();
  for (int i = blockIdx.x*256 + threadIdx.x; i < NN; i += CBLOCKS*256) {
    int bk = height[i]*NTYPE + dep_type[i];
    int pos = atomicAdd(&cnt[bk], 1);
    ib[NODE_LIST + base[bk] + pos] = i;
  }
}

// Per-sentence CSR of children (parents are sentence-local). Deterministic:
// rank of child = #earlier siblings. No global atomics.
__global__ __launch_bounds__(128) void csr_kernel(const int* __restrict__ parent,
    int* ib) {
  __shared__ int par[128], startl[128], hist[128];
  int b = blockIdx.x, i = threadIdx.x;
  int p = parent[b*128 + i];              // -1 only for i==0
  par[i] = p; hist[i] = 0;
  __syncthreads();
  if (p >= 0) atomicAdd(&hist[p], 1);     // LDS atomic
  __syncthreads();
  if (i == 0) {
    int acc = 0;
    for (int u = 0; u < 128; u++) { startl[u] = acc; acc += hist[u]; }
  }
  __syncthreads();
  if (p >= 0) {
    int rank = 0;
    for (int j = 1; j < i; j++) rank += (par[j] == p);   // deterministic order
    ib[CLIST + b*128 + startl[p] + rank] = b*128 + i;
  }
  ib[CDESC + b*128 + i] = ((b*128 + startl[i]) << 8) | hist[i];
}

__device__ __forceinline__ unsigned int pack_bf16(float a, float b) {
  unsigned int ua = __float_as_uint(a); ua += 0x7fff + ((ua >> 16) & 1);
  unsigned int ub = __float_as_uint(b); ub += 0x7fff + ((ub >> 16) & 1);
  return (ua >> 16) | (ub & 0xffff0000u);
}

// fast tanh: 1 - 2*rcp(e^{2x}+1); exact at +/-inf, ~1e-6 abs error
__device__ __forceinline__ float ftanh(float x) {
  float e = __expf(2.0f * x);
  return 1.0f - 2.0f * __builtin_amdgcn_rcpf(e + 1.0f);
}

// Fragment-ordered bf16 weights for MFMA A-operand:
// wfrag[mat*2048 + mt*256 + kc*64 + lane] = uint4 of 8 bf16 =
//   W[mat][mt*16 + (lane&15)][kc*32 + (lane>>4)*8 .. +8]
__global__ __launch_bounds__(256) void wcvt_kernel(const float* __restrict__ Whr,
    const float* __restrict__ Wrel, uint4* __restrict__ wfrag) {
  int flat = blockIdx.x*256 + threadIdx.x;     // 0 .. 18431
  int lane = flat & 63;
  int kc = (flat >> 6) & 3;
  int mt = (flat >> 8) & 7;
  int mat = flat >> 11;
  int row = mt*16 + (lane & 15);
  int col = kc*32 + (lane >> 4)*8;
  const float* src = (mat == 0) ? &Whr[row*NH + col]
                                : &Wrel[(size_t)(mat-1)*NH*NH + row*NH + col];
  float4 a = *(const float4*)src;
  float4 b = *(const float4*)(src + 4);
  uint4 u;
  u.x = pack_bf16(a.x, a.y); u.y = pack_bf16(a.z, a.w);
  u.z = pack_bf16(b.x, b.y); u.w = pack_bf16(b.z, b.w);
  wfrag[flat] = u;
}

// wx = token_emb @ W_wh.T via MFMA bf16. Tile 64m x 128n, K chunks of 32 (300 pad 320).
__global__ __launch_bounds__(256) void wx_kernel(const float* __restrict__ x,
    const float* __restrict__ Wwh, float* __restrict__ wx) {
  __shared__ __align__(16) unsigned int sA[64*16];    // [row][16 uints] = 32 bf16/row
  __shared__ __align__(16) unsigned int sB[128*16];
  int tid = threadIdx.x;
  int wave = tid >> 6, lane = tid & 63;
  size_t rowbase = (size_t)blockIdx.x * 64;
  f32x4 acc[8];
  #pragma unroll
  for (int ni = 0; ni < 8; ni++) acc[ni] = (f32x4){0.f,0.f,0.f,0.f};
  for (int kc = 0; kc < 320; kc += 32) {
    __syncthreads();
    #pragma unroll
    for (int q = 0; q < 2; q++) {             // stage A: 64 rows x 8 float4
      int flat = tid + q*256; int r = flat >> 3, f4 = flat & 7;
      int k0 = kc + f4*4;
      float4 v = make_float4(0.f,0.f,0.f,0.f);
      if (k0 + 3 < NDW) v = *(const float4*)&x[(rowbase + r)*NDW + k0];
      uint2 u; u.x = pack_bf16(v.x, v.y); u.y = pack_bf16(v.z, v.w);
      *(uint2*)&sA[r*16 + f4*2] = u;
    }
    #pragma unroll
    for (int q = 0; q < 4; q++) {             // stage B: 128 rows x 8 float4
      int flat = tid + q*256; int r = flat >> 3, f4 = flat & 7;
      int k0 = kc + f4*4;
      float4 v = make_float4(0.f,0.f,0.f,0.f);
      if (k0 + 3 < NDW) v = *(const float4*)&Wwh[(size_t)r*NDW + k0];
      uint2 u; u.x = pack_bf16(v.x, v.y); u.y = pack_bf16(v.z, v.w);
      *(uint2*)&sB[r*16 + f4*2] = u;
    }
    __syncthreads();
    short8 a = *(const short8*)&sA[(wave*16 + (lane & 15))*16 + (lane >> 4)*4];
    #pragma unroll
    for (int ni = 0; ni < 8; ni++) {
      short8 b = *(const short8*)&sB[(ni*16 + (lane & 15))*16 + (lane >> 4)*4];
      acc[ni] = __builtin_amdgcn_mfma_f32_16x16x32_bf16(a, b, acc[ni], 0, 0, 0);
    }
  }
  int rbase = wave*16 + (lane >> 4)*4;
  #pragma unroll
  for (int ni = 0; ni < 8; ni++)
    #pragma unroll
    for (int reg = 0; reg < 4; reg++)
      wx[(rowbase + rbase + reg)*NH + ni*16 + (lane & 15)] = acc[ni][reg];
}

// Phase k: nodes with height==k, bucketed by dep_type t=blockIdx&7.
// One wave = 16 nodes; lanes: n = lane&15 (node slot), q2 = lane>>4 (elem block).
//   seg_i = sum over children c of einfl[c]        (gather; no atomics)
//   h_i = tanh(seg+simple)  (simple at k==0)       -> hbuf row i (write-once)
//   g = W_hr.h (MFMA); r = tanh(g + wx_parent); infl = W_rel[t].r (MFMA)
//   einfl[i] = infl                                (plain coalesced store)
struct PerWave {
  union {
    unsigned short pan[16][136];   // bf16 MFMA B-panel
    float pan32[16][132];          // fp32 store staging (time-separated reuse)
  } u;
};

__global__ __launch_bounds__(256, 4) void phase_kernel(
    const uint4* __restrict__ wfrag, const float* __restrict__ bwh,
    const float* __restrict__ wx, const int* __restrict__ parent,
    const int* __restrict__ ib, float* hbuf, float* einfl, int k) {
  int t = blockIdx.x & 7, sub = blockIdx.x >> 3;     // 128 subs per type
  int bs = ib[OFF + k*NTYPE + t];
  int be = ib[OFF + k*NTYPE + t + 1];
  int nbat = (be - bs + 15) >> 4;
  if (sub*4 >= nbat) return;                         // uniform early-exit
  __shared__ __align__(16) PerWave sP[4];            // ~34 KB
  __shared__ int srow[4][16];
  int wave = threadIdx.x >> 6, lane = threadIdx.x & 63;
  int n = lane & 15, q2 = lane >> 4;
  const uint4* whrF  = wfrag;                        // mat 0
  const uint4* wrelF = wfrag + (size_t)(1 + t)*2048; // mat 1+t
  unsigned short (*pan)[136] = sP[wave].u.pan;
  float (*pan32)[132] = sP[wave].u.pan32;

  for (int b = sub*4 + wave; b < nbat; b += 512) {
    int base = bs + b*16;
    int it = base + n;
    bool valid = it < be;
    if (!valid) it = be - 1;                         // clamp: duplicate, masked later
    int i = ib[NODE_LIST + it];
    // ---- gather own 32 elements, compute simple ----
    float4 hh[8];
    #pragma unroll
    for (int q = 0; q < 8; q++) {
      float4 xv = *(const float4*)&wx[(size_t)i*NH + q2*32 + q*4];
      float4 bv = *(const float4*)&bwh[q2*32 + q*4];
      hh[q].x = ftanh(xv.x + bv.x); hh[q].y = ftanh(xv.y + bv.y);
      hh[q].z = ftanh(xv.z + bv.z); hh[q].w = ftanh(xv.w + bv.w);
    }
    if (k > 0) {
      // ---- seg = sum of children einfl rows (CSR gather, no atomics) ----
      int cd = ib[CDESC + i];
      int cs = cd >> 8, cc = cd & 255;
      float4 seg[8];
      #pragma unroll
      for (int q = 0; q < 8; q++) seg[q] = make_float4(0.f,0.f,0.f,0.f);
      for (int ci = 0; ci < cc; ci++) {              // uniform per 4-lane group
        int c = ib[CLIST + cs + ci];
        const float* er = &einfl[(size_t)c*NH + q2*32];
        #pragma unroll
        for (int q = 0; q < 8; q++) {
          float4 v = *(const float4*)&er[q*4];
          seg[q].x += v.x; seg[q].y += v.y; seg[q].z += v.z; seg[q].w += v.w;
        }
      }
      #pragma unroll
      for (int q = 0; q < 8; q++) {
        hh[q].x = ftanh(seg[q].x + hh[q].x); hh[q].y = ftanh(seg[q].y + hh[q].y);
        hh[q].z = ftanh(seg[q].z + hh[q].z); hh[q].w = ftanh(seg[q].w + hh[q].w);
      }
    }
    if (valid) {
      #pragma unroll
      for (int q = 0; q < 8; q++)
        *(float4*)&hbuf[(size_t)i*NH + q2*32 + q*4] = hh[q];   // final h (write-once)
    }
    // ---- pack h into bf16 panel: row n, chunks q2*4 .. q2*4+3 ----
    #pragma unroll
    for (int c = 0; c < 4; c++) {
      uint4 u;
      u.x = pack_bf16(hh[c*2].x,   hh[c*2].y);
      u.y = pack_bf16(hh[c*2].z,   hh[c*2].w);
      u.z = pack_bf16(hh[c*2+1].x, hh[c*2+1].y);
      u.w = pack_bf16(hh[c*2+1].z, hh[c*2+1].w);
      *(uint4*)&pan[n][(q2*4 + c)*8] = u;
    }
    // ---- parent id; einfl target = own row (publish to LDS) ----
    int p = parent[i];
    bool hasp = valid && p >= 0;
    if (q2 == 0) srow[wave][n] = hasp ? i : -1;
    int psafe = hasp ? (i & ~(NT-1)) + p : i;
    float4 pw[8];
    #pragma unroll
    for (int mt = 0; mt < 8; mt++)
      pw[mt] = *(const float4*)&wx[(size_t)psafe*NH + mt*16 + q2*4];
    // ---- matvec1: g = W_hr . h  (32 MFMA) ----
    uint4 bf[4];
    #pragma unroll
    for (int kc = 0; kc < 4; kc++)
      bf[kc] = *(const uint4*)&pan[n][(kc*4 + q2)*8];
    f32x4 acc[8];
    #pragma unroll
    for (int mt = 0; mt < 8; mt++) acc[mt] = (f32x4){0.f,0.f,0.f,0.f};
    #pragma unroll
    for (int mt = 0; mt < 8; mt++)
      #pragma unroll
      for (int kc = 0; kc < 4; kc++) {
        U16 af; af.u = whrF[(mt*4 + kc)*64 + lane];
        U16 bb; bb.u = bf[kc];
        acc[mt] = __builtin_amdgcn_mfma_f32_16x16x32_bf16(af.s, bb.s, acc[mt], 0, 0, 0);
      }
    // ---- r = tanh(g + wx_parent), repack panel (C-layout) ----
    #pragma unroll
    for (int mt = 0; mt < 8; mt++) {
      float r0 = ftanh(acc[mt][0] + pw[mt].x);
      float r1 = ftanh(acc[mt][1] + pw[mt].y);
      float r2 = ftanh(acc[mt][2] + pw[mt].z);
      float r3 = ftanh(acc[mt][3] + pw[mt].w);
      uint2 u2; u2.x = pack_bf16(r0, r1); u2.y = pack_bf16(r2, r3);
      *(uint2*)&pan[n][mt*16 + q2*4] = u2;
    }
    // ---- matvec2: infl = W_rel[t] . r  (32 MFMA) ----
    #pragma unroll
    for (int kc = 0; kc < 4; kc++)
      bf[kc] = *(const uint4*)&pan[n][(kc*4 + q2)*8];
    f32x4 acc2[8];
    #pragma unroll
    for (int mt = 0; mt < 8; mt++) acc2[mt] = (f32x4){0.f,0.f,0.f,0.f};
    #pragma unroll
    for (int mt = 0; mt < 8; mt++)
      #pragma unroll
      for (int kc = 0; kc < 4; kc++) {
        U16 af; af.u = wrelF[(mt*4 + kc)*64 + lane];
        U16 bb; bb.u = bf[kc];
        acc2[mt] = __builtin_amdgcn_mfma_f32_16x16x32_bf16(af.s, bb.s, acc2[mt], 0, 0, 0);
      }
    // ---- stage to fp32 panel, then row-coalesced PLAIN stores to einfl ----
    #pragma unroll
    for (int mt = 0; mt < 8; mt++)
      *(float4*)&pan32[n][mt*16 + q2*4] =
          make_float4(acc2[mt][0], acc2[mt][1], acc2[mt][2], acc2[mt][3]);
    #pragma unroll 4
    for (int j = 0; j < 16; j++) {
      int r = srow[wave][j];
      if (r >= 0) {                                  // wave-uniform branch
        float2 v = *(const float2*)&pan32[j][2*lane];
        *(float2*)&einfl[(size_t)r*NH + 2*lane] = v;
      }
    }
  }
}

extern "C" void kernel_launch(void* const* d_in, const int* in_sizes, int n_in,
                              void* d_out, int out_size, void* d_ws, size_t ws_size,
                              hipStream_t stream) {
  const float* token  = (const float*)d_in[0];
  const float* Wwh    = (const float*)d_in[1];
  const float* bwh    = (const float*)d_in[2];
  const float* Whr    = (const float*)d_in[3];
  const float* Wrel   = (const float*)d_in[4];
  const int*   parent = (const int*)d_in[5];
  const int*   dep    = (const int*)d_in[6];
  const int*   height = (const int*)d_in[7];

  float* hbuf  = (float*)d_out;                         // final h only (write-once)
  float* wx    = (float*)d_ws;                          // [NN,NH] f32, 16MB
  float* einfl = (float*)((char*)d_ws + 16777216);      // [NN,NH] f32, 16MB
  int*   ib    = (int*)((char*)d_ws + 33554432);        // sort + CSR (~447KB)
  uint4* wfrag = (uint4*)((char*)d_ws + 33554432 + 458752); // 288KB frag weights

  wcvt_kernel<<<72, 256, 0, stream>>>(Whr, Wrel, wfrag);
  count_kernel<<<CBLOCKS, 256, 0, stream>>>(dep, height, ib);
  scan_kernel<<<1, 128, 0, stream>>>(ib);
  scatter_kernel<<<CBLOCKS, 256, 0, stream>>>(dep, height, ib);
  csr_kernel<<<NB, 128, 0, stream>>>(parent, ib);
  wx_kernel<<<NN/64, 256, 0, stream>>>(token, Wwh, wx);
  for (int k = 0; k < NLEVEL; k++)
    phase_kernel<<<PBLOCKS, 256, 0, stream>>>(wfrag, bwh, wx, parent, ib, hbuf, einfl, k);
}

// Round 14
// 385.715 us; speedup vs baseline: 1.4727x; 1.4727x over previous
//
#include <hip/hip_runtime.h>
#include <math.h>

#define NB 256
#define NT 128
#define NDW 300
#define NH 128
#define NTYPE 8
#define NLEVEL 13
#define NN (NB*NT)

#define NBK 104       // (height 0..12) x (type 0..7) node buckets
#define CBLOCKS 64
#define PBLOCKS 2048  // phase grid: 256 subs per type x 8 types

// ib layout (ints), at byte offset 16MB of d_ws
#define BC 0                    // [CBLOCKS][NBK] per-block counts
#define BB 8192                 // [CBLOCKS][NBK] per-block base offsets
#define OFF 16384               // [NBK+1] bucket starts
#define NODE_LIST 16512         // [NN] int2 {node, parent_global or -1}

typedef __attribute__((ext_vector_type(8))) short short8;
typedef __attribute__((ext_vector_type(4))) float f32x4;

__global__ __launch_bounds__(256) void count_kernel(const int* __restrict__ dep_type,
    const int* __restrict__ height, int* ib) {
  __shared__ int cnt[NBK];
  for (int u = threadIdx.x; u < NBK; u += 256) cnt[u] = 0;
  __syncthreads();
  for (int i = blockIdx.x*256 + threadIdx.x; i < NN; i += CBLOCKS*256)
    atomicAdd(&cnt[height[i]*NTYPE + dep_type[i]], 1);
  __syncthreads();
  for (int u = threadIdx.x; u < NBK; u += 256)
    ib[BC + blockIdx.x*NBK + u] = cnt[u];
}

__global__ __launch_bounds__(128) void scan_kernel(int* ib) {
  __shared__ int total[NBK], start[NBK];
  int u = threadIdx.x;
  if (u < NBK) {
    int acc = 0;
    for (int b = 0; b < CBLOCKS; b++) {
      ib[BB + b*NBK + u] = acc;
      acc += ib[BC + b*NBK + u];
    }
    total[u] = acc;
  }
  __syncthreads();
  if (u == 0) {
    int acc = 0;
    for (int e = 0; e < NBK; e++) { start[e] = acc; ib[OFF+e] = acc; acc += total[e]; }
    ib[OFF+NBK] = acc;
  }
  __syncthreads();
  if (u < NBK) {
    int s = start[u];
    for (int b = 0; b < CBLOCKS; b++) ib[BB + b*NBK + u] += s;
  }
}

__global__ __launch_bounds__(256) void scatter_kernel(const int* __restrict__ parent,
    const int* __restrict__ dep_type, const int* __restrict__ height, int* ib) {
  __shared__ int base[NBK];
  __shared__ int cnt[NBK];
  int2* nl = (int2*)&ib[NODE_LIST];
  for (int u = threadIdx.x; u < NBK; u += 256) {
    base[u] = ib[BB + blockIdx.x*NBK + u];
    cnt[u] = 0;
  }
  __syncthreads();
  for (int i = blockIdx.x*256 + threadIdx.x; i < NN; i += CBLOCKS*256) {
    int bk = height[i]*NTYPE + dep_type[i];
    int pos = atomicAdd(&cnt[bk], 1);
    int p = parent[i];
    int pg = p >= 0 ? (i & ~(NT-1)) + p : -1;
    nl[base[bk] + pos] = make_int2(i, pg);
  }
}

__device__ __forceinline__ unsigned int pack_bf16(float a, float b) {
  unsigned int ua = __float_as_uint(a); ua += 0x7fff + ((ua >> 16) & 1);
  unsigned int ub = __float_as_uint(b); ub += 0x7fff + ((ub >> 16) & 1);
  return (ua >> 16) | (ub & 0xffff0000u);
}

// fast tanh: 1 - 2*rcp(e^{2x}+1); exact at +/-inf, ~1e-6 abs error
__device__ __forceinline__ float ftanh(float x) {
  float e = __expf(2.0f * x);
  return 1.0f - 2.0f * __builtin_amdgcn_rcpf(e + 1.0f);
}

// Transposed-packed bf16 weights: bwT[mat][d4][row] = uint2 of 4 bf16 =
// W[mat][row][4*d4..4*d4+3]. mat 0 = W_hr, mat 1+t = W_rel[t]. Coalesced build.
__global__ __launch_bounds__(256) void wcvt_kernel(const float* __restrict__ Whr,
    const float* __restrict__ Wrel, uint2* __restrict__ bwT) {
  int flat = blockIdx.x*256 + threadIdx.x;     // 0 .. 9*4096-1
  int mat = flat >> 12, rem = flat & 4095;
  int d4 = rem >> 7, row = rem & 127;
  const float* src = (mat == 0) ? &Whr[row*NH + d4*4]
                                : &Wrel[(size_t)(mat-1)*NH*NH + row*NH + d4*4];
  float4 v = *(const float4*)src;
  uint2 u; u.x = pack_bf16(v.x, v.y); u.y = pack_bf16(v.z, v.w);
  bwT[flat] = u;
}

// wx = token_emb @ W_wh.T via MFMA bf16. Tile 64m x 128n, K chunks of 32 (300 pad 320).
__global__ __launch_bounds__(256) void wx_kernel(const float* __restrict__ x,
    const float* __restrict__ Wwh, float* __restrict__ wx, float* __restrict__ hbuf) {
  __shared__ __align__(16) unsigned int sA[64*16];    // [row][16 uints] = 32 bf16/row
  __shared__ __align__(16) unsigned int sB[128*16];
  int tid = threadIdx.x;
  int wave = tid >> 6, lane = tid & 63;
  size_t rowbase = (size_t)blockIdx.x * 64;
  f32x4 acc[8];
  #pragma unroll
  for (int ni = 0; ni < 8; ni++) acc[ni] = (f32x4){0.f,0.f,0.f,0.f};
  for (int kc = 0; kc < 320; kc += 32) {
    __syncthreads();
    #pragma unroll
    for (int q = 0; q < 2; q++) {             // stage A: 64 rows x 8 float4
      int flat = tid + q*256; int r = flat >> 3, f4 = flat & 7;
      int k0 = kc + f4*4;
      float4 v = make_float4(0.f,0.f,0.f,0.f);
      if (k0 + 3 < NDW) v = *(const float4*)&x[(rowbase + r)*NDW + k0];
      uint2 u; u.x = pack_bf16(v.x, v.y); u.y = pack_bf16(v.z, v.w);
      *(uint2*)&sA[r*16 + f4*2] = u;
    }
    #pragma unroll
    for (int q = 0; q < 4; q++) {             // stage B: 128 rows x 8 float4
      int flat = tid + q*256; int r = flat >> 3, f4 = flat & 7;
      int k0 = kc + f4*4;
      float4 v = make_float4(0.f,0.f,0.f,0.f);
      if (k0 + 3 < NDW) v = *(const float4*)&Wwh[(size_t)r*NDW + k0];
      uint2 u; u.x = pack_bf16(v.x, v.y); u.y = pack_bf16(v.z, v.w);
      *(uint2*)&sB[r*16 + f4*2] = u;
    }
    __syncthreads();
    short8 a = *(const short8*)&sA[(wave*16 + (lane & 15))*16 + (lane >> 4)*4];
    #pragma unroll
    for (int ni = 0; ni < 8; ni++) {
      short8 b = *(const short8*)&sB[(ni*16 + (lane & 15))*16 + (lane >> 4)*4];
      acc[ni] = __builtin_amdgcn_mfma_f32_16x16x32_bf16(a, b, acc[ni], 0, 0, 0);
    }
  }
  int rbase = wave*16 + (lane >> 4)*4;
  #pragma unroll
  for (int ni = 0; ni < 8; ni++)
    #pragma unroll
    for (int reg = 0; reg < 4; reg++)
      wx[(rowbase + rbase + reg)*NH + ni*16 + (lane & 15)] = acc[ni][reg];
  float4 z = make_float4(0.f,0.f,0.f,0.f);
  #pragma unroll
  for (int q = 0; q < 8; q++) {
    int flat = tid + q*256; int r = flat >> 5, c = flat & 31;
    *(float4*)&hbuf[(rowbase + r)*NH + c*4] = z;
  }
}

// 4-node batched matvec, float2 lane mapping: lane owns output rows 2l,2l+1.
// One uint4 load per d4 serves both rows (adjacent in transposed table).
__device__ __forceinline__ void matvec4_T2(const uint2* __restrict__ wt,
    int lane, const float (*sv)[NH], float* o0, float* o1) {
  #pragma unroll
  for (int j = 0; j < 4; j++) { o0[j] = 0.f; o1[j] = 0.f; }
  #pragma unroll 4
  for (int d4 = 0; d4 < 32; d4++) {
    uint4 u = *(const uint4*)&wt[d4*128 + 2*lane];   // rows 2l (x,y), 2l+1 (z,w)
    float w00 = __uint_as_float(u.x << 16), w01 = __uint_as_float(u.x & 0xffff0000u);
    float w02 = __uint_as_float(u.y << 16), w03 = __uint_as_float(u.y & 0xffff0000u);
    float w10 = __uint_as_float(u.z << 16), w11 = __uint_as_float(u.z & 0xffff0000u);
    float w12 = __uint_as_float(u.w << 16), w13 = __uint_as_float(u.w & 0xffff0000u);
    #pragma unroll
    for (int j = 0; j < 4; j++) {
      float4 v = *(const float4*)&sv[j][d4*4];    // wave-uniform: LDS broadcast
      o0[j] += w00*v.x + w01*v.y + w02*v.z + w03*v.w;
      o1[j] += w10*v.x + w11*v.y + w12*v.z + w13*v.w;
    }
  }
}

// Phase k: nodes with height==k, bucketed by dep_type t=blockIdx&7:
//   h_i = tanh(hbuf_i + simple_i)  (simple_i at k==0) -> hbuf_i final
//   g_i = W_hr.h_i ; r = tanh(g_i + wx_parent); infl = W_rel[t].r -> atomicAdd hbuf[parent]
// j=4, float2 lane mapping, coalesced bf16 weights; LDS 8KB; 8 blocks/CU (32 waves).
__global__ __launch_bounds__(256, 8) void phase_kernel(
    const uint2* __restrict__ bwT, const float* __restrict__ bwh,
    const float* __restrict__ wx, const int* __restrict__ ib,
    float* __restrict__ hbuf, int k) {
  int t = blockIdx.x & 7, sub = blockIdx.x >> 3;     // 256 subs per type
  int bs = ib[OFF + k*NTYPE + t];
  int be = ib[OFF + k*NTYPE + t + 1];
  int nbat = (be - bs + 3) >> 2;
  if (sub*4 >= nbat) return;                         // uniform early-exit
  __shared__ __align__(16) float sh[4][4][NH];       // 8 KB
  const int2* nl = (const int2*)&ib[NODE_LIST];
  int wave = threadIdx.x >> 6, lane = threadIdx.x & 63;
  int e0 = 2*lane;                                   // lane owns elements e0, e0+1
  const uint2* whr_t  = bwT;                         // mat 0
  const uint2* wrel_t = bwT + (size_t)(1 + t)*4096;  // mat 1+t
  float2 bv = *(const float2*)&bwh[e0];
  for (int b = sub*4 + wave; b < nbat; b += 256*4) {
    int base = bs + b*4;
    int cnt = be - base; if (cnt > 4) cnt = 4;
    int2 np[4];
    // pass 1: node records (node idx + precomputed global parent)
    #pragma unroll
    for (int j = 0; j < 4; j++) {
      int it = base + j; if (it >= be) it = be - 1;  // clamp tail (wave-uniform)
      np[j] = nl[it];
    }
    // pass 2: ALL row loads issued back-to-back (one round trip, max in flight)
    float2 wxv[4], hb[4], pw[4];
    #pragma unroll
    for (int j = 0; j < 4; j++)
      wxv[j] = *(const float2*)&wx[(size_t)np[j].x*NH + e0];
    #pragma unroll
    for (int j = 0; j < 4; j++) {
      int p = np[j].y >= 0 ? np[j].y : np[j].x;
      pw[j] = *(const float2*)&wx[(size_t)p*NH + e0];
    }
    if (k > 0) {
      #pragma unroll
      for (int j = 0; j < 4; j++)
        hb[j] = *(const float2*)&hbuf[(size_t)np[j].x*NH + e0];
    }
    // finalize h, publish to LDS + hbuf
    #pragma unroll
    for (int j = 0; j < 4; j++) {
      float s0 = ftanh(wxv[j].x + bv.x);
      float s1 = ftanh(wxv[j].y + bv.y);
      float h0, h1;
      if (k == 0) { h0 = s0; h1 = s1; }
      else { h0 = ftanh(hb[j].x + s0); h1 = ftanh(hb[j].y + s1); }
      if (j < cnt)
        *(float2*)&hbuf[(size_t)np[j].x*NH + e0] = make_float2(h0, h1);  // final h
      *(float2*)&sh[wave][j][e0] = make_float2(h0, h1);   // wave-synchronous LDS
    }
    float g0[4], g1[4];
    matvec4_T2(whr_t, lane, sh[wave], g0, g1);       // g = W_hr . h
    #pragma unroll
    for (int j = 0; j < 4; j++) {                    // r = tanh(g + wx_parent)
      float r0 = ftanh(g0[j] + pw[j].x);
      float r1 = ftanh(g1[j] + pw[j].y);
      *(float2*)&sh[wave][j][e0] = make_float2(r0, r1);
    }
    float o0[4], o1[4];
    matvec4_T2(wrel_t, lane, sh[wave], o0, o1);      // infl = W_rel[t] . r
    #pragma unroll
    for (int j = 0; j < 4; j++) if (j < cnt && np[j].y >= 0) {
      atomicAdd(&hbuf[(size_t)np[j].y*NH + e0],     o0[j]);
      atomicAdd(&hbuf[(size_t)np[j].y*NH + e0 + 1], o1[j]);
    }
  }
}

extern "C" void kernel_launch(void* const* d_in, const int* in_sizes, int n_in,
                              void* d_out, int out_size, void* d_ws, size_t ws_size,
                              hipStream_t stream) {
  const float* token  = (const float*)d_in[0];
  const float* Wwh    = (const float*)d_in[1];
  const float* bwh    = (const float*)d_in[2];
  const float* Whr    = (const float*)d_in[3];
  const float* Wrel   = (const float*)d_in[4];
  const int*   parent = (const int*)d_in[5];
  const int*   dep    = (const int*)d_in[6];
  const int*   height = (const int*)d_in[7];

  float* hbuf = (float*)d_out;                          // seg-accumulator, then final h
  float* wx   = (float*)d_ws;                           // [NN,NH] f32, 16MB
  int*   ib   = (int*)((char*)d_ws + 16777216);         // bucket metadata + node list
  uint2* bwT  = (uint2*)((char*)d_ws + 16777216 + 1048576);  // 9*32KB bf16 weights

  wcvt_kernel<<<144, 256, 0, stream>>>(Whr, Wrel, bwT);
  count_kernel<<<CBLOCKS, 256, 0, stream>>>(dep, height, ib);
  scan_kernel<<<1, 128, 0, stream>>>(ib);
  scatter_kernel<<<CBLOCKS, 256, 0, stream>>>(parent, dep, height, ib);
  wx_kernel<<<NN/64, 256, 0, stream>>>(token, Wwh, wx, hbuf);
  for (int k = 0; k < NLEVEL; k++)
    phase_kernel<<<PBLOCKS, 256, 0, stream>>>(bwT, bwh, wx, ib, hbuf, k);
}